// Round 1
// baseline (980.923 us; speedup 1.0000x reference)
//
#include <hip/hip_runtime.h>
#include <math.h>
#include <stdint.h>

#define HW 16777216u
#define CAP 16384u

// ---------------- threefry2x32 (JAX-compatible, 20 rounds) ----------------
__host__ __device__ inline uint32_t tf_rotl(uint32_t x, int n){ return (x<<n)|(x>>(32-n)); }

__host__ __device__ inline void threefry2x32(uint32_t k0, uint32_t k1, uint32_t x0, uint32_t x1,
                                             uint32_t &o0, uint32_t &o1){
  uint32_t ks2 = k0 ^ k1 ^ 0x1BD11BDAu;
  x0 += k0; x1 += k1;
#define TF_R4(a,b,c,d) \
  x0 += x1; x1 = tf_rotl(x1,(a)); x1 ^= x0; \
  x0 += x1; x1 = tf_rotl(x1,(b)); x1 ^= x0; \
  x0 += x1; x1 = tf_rotl(x1,(c)); x1 ^= x0; \
  x0 += x1; x1 = tf_rotl(x1,(d)); x1 ^= x0;
  TF_R4(13,15,26,6)  x0 += k1;  x1 += ks2 + 1u;
  TF_R4(17,29,16,24) x0 += ks2; x1 += k0  + 2u;
  TF_R4(13,15,26,6)  x0 += k0;  x1 += k1  + 3u;
  TF_R4(17,29,16,24) x0 += k1;  x1 += ks2 + 4u;
  TF_R4(13,15,26,6)  x0 += ks2; x1 += k0  + 5u;
#undef TF_R4
  o0 = x0; o1 = x1;
}

// order-preserving uint mapping for floats (ascending)
__device__ __forceinline__ uint32_t okey(float f){
  uint32_t b = __float_as_uint(f);
  return (b & 0x80000000u) ? ~b : (b | 0x80000000u);
}

// state layout (u32 indices into st):
// st[0]=S ; sel s in {0:fg_cand,1:bg_cand,2:fg_score,3:bg_score} at base 8+8*s:
//   +0 d1, +1 rem1, +2 d2, +3 rem2, +4 T(okey), +5 cut_idx, +6 rem3

// --------------- pass 1 (cand): roi sum + level-1 hists -------------------
__global__ void k_hist1_cand(const float* __restrict__ cam, const int* __restrict__ roi,
                             unsigned* __restrict__ h1a, unsigned* __restrict__ h1b,
                             unsigned* __restrict__ st){
  __shared__ unsigned la[4096], lb[4096];
  __shared__ unsigned ssum;
  for (int j = threadIdx.x; j < 4096; j += blockDim.x){ la[j]=0u; lb[j]=0u; }
  if (threadIdx.x==0) ssum = 0u;
  __syncthreads();
  unsigned tid = blockIdx.x*blockDim.x + threadIdx.x;
  unsigned stride = gridDim.x*blockDim.x;
  unsigned s_local = 0u;
  for (unsigned i = tid; i < HW; i += stride){
    float c = cam[i]; int r = roi[i];
    s_local += (unsigned)r;
    float vfg = c * (float)r + 1e-8f;
    float vbg = c + 1e-8f;
    atomicAdd(&la[okey(vfg)>>20], 1u);
    atomicAdd(&lb[okey(vbg)>>20], 1u);
  }
  atomicAdd(&ssum, s_local);
  __syncthreads();
  for (int j = threadIdx.x; j < 4096; j += blockDim.x){
    unsigned va = la[j], vb = lb[j];
    if (va) atomicAdd(&h1a[j], va);
    if (vb) atomicAdd(&h1b[j], vb);
  }
  if (threadIdx.x==0) atomicAdd(&st[0], ssum);
}

// --------------- block-cooperative select over 4096-bin hist --------------
__device__ void block_select4096(const unsigned* __restrict__ h, unsigned n, bool top,
                                 unsigned* out_bin, unsigned* out_rem){
  __shared__ unsigned csum[256];
  __shared__ unsigned sb, sr;
  unsigned t = threadIdx.x;
  unsigned s = 0u;
  #pragma unroll
  for (int j = 0; j < 16; j++) s += h[t*16 + j];
  csum[t] = s;
  __syncthreads();
  if (t == 0){
    unsigned rem = n; int c;
    if (top){ for (c = 255; c >= 0; c--){ if (csum[c] >= rem) break; rem -= csum[c]; } }
    else    { for (c = 0; c < 256; c++){ if (csum[c] >= rem) break; rem -= csum[c]; } }
    int b;
    if (top){ for (b = c*16+15; b > c*16; b--){ if (h[b] >= rem) break; rem -= h[b]; } }
    else    { for (b = c*16; b < c*16+15; b++){ if (h[b] >= rem) break; rem -= h[b]; } }
    sb = (unsigned)b; sr = rem;
  }
  __syncthreads();
  *out_bin = sb; *out_rem = sr;
  __syncthreads();  // safe reuse of shared on next call
}

__global__ void k_fin1(const unsigned* __restrict__ h1a, const unsigned* __restrict__ h1b,
                       unsigned* __restrict__ st, int round){
  unsigned nA, nB; bool topA, topB; int bA, bB;
  if (round == 0){
    nA = (unsigned)(0.2f * (float)st[0]);  // trunc toward zero, f32 mult like jnp
    topA = true;  bA = 8;
    nB = 1677721u; topB = false; bB = 16;
  } else {
    nA = 5000u; nB = 5000u; topA = topB = true; bA = 24; bB = 32;
  }
  unsigned bin, rem;
  block_select4096(h1a, nA, topA, &bin, &rem);
  if (threadIdx.x==0){ st[bA+0]=bin; st[bA+1]=rem; }
  __syncthreads();
  block_select4096(h1b, nB, topB, &bin, &rem);
  if (threadIdx.x==0){ st[bB+0]=bin; st[bB+1]=rem; }
}

__global__ void k_fin2(const unsigned* __restrict__ h2a, const unsigned* __restrict__ h2b,
                       unsigned* __restrict__ st, int round){
  int bA = (round==0) ? 8 : 24;
  int bB = (round==0) ? 16 : 32;
  bool topA = true, topB = (round==0) ? false : true;
  unsigned bin, rem;
  block_select4096(h2a, st[bA+1], topA, &bin, &rem);
  if (threadIdx.x==0){ st[bA+2]=bin; st[bA+3]=rem; }
  __syncthreads();
  block_select4096(h2b, st[bB+1], topB, &bin, &rem);
  if (threadIdx.x==0){ st[bB+2]=bin; st[bB+3]=rem; }
}

// --------------- pass 2 (cand): level-2 hists within selected prefix ------
__global__ void k_hist2_cand(const float* __restrict__ cam, const int* __restrict__ roi,
                             const unsigned* __restrict__ st,
                             unsigned* __restrict__ h2a, unsigned* __restrict__ h2b){
  __shared__ unsigned la[4096], lb[4096];
  for (int j = threadIdx.x; j < 4096; j += blockDim.x){ la[j]=0u; lb[j]=0u; }
  __syncthreads();
  unsigned pa = st[8], pb = st[16];
  unsigned tid = blockIdx.x*blockDim.x + threadIdx.x;
  unsigned stride = gridDim.x*blockDim.x;
  for (unsigned i = tid; i < HW; i += stride){
    float c = cam[i]; int r = roi[i];
    unsigned okf = okey(c * (float)r + 1e-8f);
    unsigned okb = okey(c + 1e-8f);
    if ((okf>>20) == pa) atomicAdd(&la[(okf>>8)&0xFFFu], 1u);
    if ((okb>>20) == pb) atomicAdd(&lb[(okb>>8)&0xFFFu], 1u);
  }
  __syncthreads();
  for (int j = threadIdx.x; j < 4096; j += blockDim.x){
    unsigned va = la[j], vb = lb[j];
    if (va) atomicAdd(&h2a[j], va);
    if (vb) atomicAdd(&h2b[j], vb);
  }
}

// --------------- pass 3 (cand): collect 24-bit-prefix matches -------------
__global__ void k_col_cand(const float* __restrict__ cam, const int* __restrict__ roi,
                           const unsigned* __restrict__ st,
                           unsigned long long* __restrict__ colA,
                           unsigned long long* __restrict__ colB,
                           unsigned* __restrict__ cnt){
  unsigned p24a = (st[8]<<12) | st[10];
  unsigned p24b = (st[16]<<12) | st[18];
  unsigned tid = blockIdx.x*blockDim.x + threadIdx.x;
  unsigned stride = gridDim.x*blockDim.x;
  for (unsigned i = tid; i < HW; i += stride){
    float c = cam[i]; int r = roi[i];
    unsigned okf = okey(c * (float)r + 1e-8f);
    unsigned okb = okey(c + 1e-8f);
    if ((okf>>8) == p24a){
      unsigned p = atomicAdd(&cnt[0], 1u);
      if (p < CAP) colA[p] = ((unsigned long long)(okf & 0xFFu) << 32) | i;
    }
    if ((okb>>8) == p24b){
      unsigned p = atomicAdd(&cnt[1], 1u);
      if (p < CAP) colB[p] = ((unsigned long long)(okb & 0xFFu) << 32) | i;
    }
  }
}

// --------------- finalize level 3: exact threshold + tie cutoff -----------
__global__ void k_fin3(const unsigned long long* __restrict__ colA,
                       const unsigned long long* __restrict__ colB,
                       const unsigned* __restrict__ cnt,
                       unsigned* __restrict__ st, int round){
  __shared__ unsigned h[256];
  __shared__ unsigned s_d3, s_rem;
  for (int side = 0; side < 2; side++){
    int base = (round==0) ? (side==0 ? 8 : 16) : (side==0 ? 24 : 32);
    bool top = (round==0) ? (side==0) : true;
    const unsigned long long* col = side ? colB : colA;
    unsigned m = cnt[side]; if (m > CAP) m = CAP;
    unsigned n = st[base+3];  // rem2
    for (int j = threadIdx.x; j < 256; j += blockDim.x) h[j] = 0u;
    __syncthreads();
    for (unsigned e = threadIdx.x; e < m; e += blockDim.x)
      atomicAdd(&h[(unsigned)(col[e]>>32) & 0xFFu], 1u);
    __syncthreads();
    if (threadIdx.x == 0){
      unsigned rem = n; int b;
      if (top){ for (b = 255; b > 0; b--){ if (h[b] >= rem) break; rem -= h[b]; } }
      else    { for (b = 0; b < 255; b++){ if (h[b] >= rem) break; rem -= h[b]; } }
      s_d3 = (unsigned)b; s_rem = rem;
    }
    __syncthreads();
    unsigned d3 = s_d3, rem3 = s_rem;
    for (unsigned e = threadIdx.x; e < m; e += blockDim.x){
      unsigned long long v = col[e];
      if (((unsigned)(v>>32) & 0xFFu) == d3){
        unsigned idx = (unsigned)(v & 0xFFFFFFFFu);
        unsigned rank = 0;
        for (unsigned j = 0; j < m; j++){
          unsigned long long w = col[j];
          if (((unsigned)(w>>32) & 0xFFu) == d3 && (unsigned)(w & 0xFFFFFFFFu) < idx) rank++;
        }
        if (rank == rem3 - 1u){
          st[base+4] = (st[base+0]<<20) | (st[base+2]<<8) | d3;
          st[base+5] = idx;
          st[base+6] = rem3;
        }
      }
    }
    __syncthreads();
  }
}

// --------------- score computation (exact JAX arithmetic) -----------------
__device__ __forceinline__ float gumbel_score(uint32_t kk0, uint32_t kk1, uint32_t i, float prob){
  uint32_t y0, y1; threefry2x32(kk0, kk1, 0u, i, y0, y1);
  uint32_t bits = y0 ^ y1;                       // partitionable 32-bit fold
  float f = __uint_as_float((bits>>9) | 0x3F800000u) - 1.0f;
  float u = fmaxf(1e-12f, f + 1e-12f);           // floats*(1.0f)+minval, then max
  float l1 = (float)log((double)u);              // jnp.log(u)       (f32-rounded)
  float l2 = (float)log((double)(-l1));          // jnp.log(-log(u)) (f32-rounded)
  float lp = (float)log((double)prob);           // jnp.log(probs)   (f32-rounded)
  return lp - l2;
}

__global__ void k_score(const float* __restrict__ cam, const int* __restrict__ roi,
                        const unsigned* __restrict__ st, float* __restrict__ out,
                        unsigned* __restrict__ h1a, unsigned* __restrict__ h1b,
                        uint32_t kf0, uint32_t kf1, uint32_t kb0, uint32_t kb1){
  __shared__ unsigned la[4096], lb[4096];
  for (int j = threadIdx.x; j < 4096; j += blockDim.x){ la[j]=0u; lb[j]=0u; }
  __syncthreads();
  unsigned Ta = st[12], ca = st[13];  // fg cand threshold okey + tie cutoff
  unsigned Tb = st[20], cb = st[21];  // bg cand
  unsigned tid = blockIdx.x*blockDim.x + threadIdx.x;
  unsigned stride = gridDim.x*blockDim.x;
  for (unsigned i = tid; i < HW; i += stride){
    float c = cam[i]; int r = roi[i];
    float vfg = c * (float)r + 1e-8f;
    unsigned okf = okey(vfg);
    float sf;
    if (okf > Ta || (okf == Ta && i <= ca)) sf = gumbel_score(kf0, kf1, i, vfg);
    else sf = -INFINITY;
    out[i] = sf;
    atomicAdd(&la[okey(sf)>>20], 1u);

    float vbg = c + 1e-8f;
    unsigned okb = okey(vbg);
    float sb;
    if (okb < Tb || (okb == Tb && i <= cb)){
      float pb = fmaxf(1.0f - vbg, 0.0f) + 1e-8f;  // relu(1-cam_bg)+eps
      sb = gumbel_score(kb0, kb1, i, pb);
    } else sb = -INFINITY;
    out[HW + i] = sb;
    atomicAdd(&lb[okey(sb)>>20], 1u);
  }
  __syncthreads();
  for (int j = threadIdx.x; j < 4096; j += blockDim.x){
    unsigned va = la[j], vb = lb[j];
    if (va) atomicAdd(&h1a[j], va);
    if (vb) atomicAdd(&h1b[j], vb);
  }
}

// --------------- score selection passes (read scores from d_out) ----------
__global__ void k_hist2_s(const float* __restrict__ out, const unsigned* __restrict__ st,
                          unsigned* __restrict__ h2a, unsigned* __restrict__ h2b){
  __shared__ unsigned la[4096], lb[4096];
  for (int j = threadIdx.x; j < 4096; j += blockDim.x){ la[j]=0u; lb[j]=0u; }
  __syncthreads();
  unsigned pa = st[24], pb = st[32];
  unsigned tid = blockIdx.x*blockDim.x + threadIdx.x;
  unsigned stride = gridDim.x*blockDim.x;
  for (unsigned i = tid; i < HW; i += stride){
    unsigned oka = okey(out[i]);
    unsigned okb = okey(out[HW + i]);
    if ((oka>>20) == pa) atomicAdd(&la[(oka>>8)&0xFFFu], 1u);
    if ((okb>>20) == pb) atomicAdd(&lb[(okb>>8)&0xFFFu], 1u);
  }
  __syncthreads();
  for (int j = threadIdx.x; j < 4096; j += blockDim.x){
    unsigned va = la[j], vb = lb[j];
    if (va) atomicAdd(&h2a[j], va);
    if (vb) atomicAdd(&h2b[j], vb);
  }
}

__global__ void k_col_s(const float* __restrict__ out, const unsigned* __restrict__ st,
                        unsigned long long* __restrict__ colA,
                        unsigned long long* __restrict__ colB,
                        unsigned* __restrict__ cnt){
  unsigned p24a = (st[24]<<12) | st[26];
  unsigned p24b = (st[32]<<12) | st[34];
  unsigned tid = blockIdx.x*blockDim.x + threadIdx.x;
  unsigned stride = gridDim.x*blockDim.x;
  for (unsigned i = tid; i < HW; i += stride){
    unsigned oka = okey(out[i]);
    unsigned okb = okey(out[HW + i]);
    if ((oka>>8) == p24a){
      unsigned p = atomicAdd(&cnt[0], 1u);
      if (p < CAP) colA[p] = ((unsigned long long)(oka & 0xFFu) << 32) | i;
    }
    if ((okb>>8) == p24b){
      unsigned p = atomicAdd(&cnt[1], 1u);
      if (p < CAP) colB[p] = ((unsigned long long)(okb & 0xFFu) << 32) | i;
    }
  }
}

// --------------- final: scores -> 0/1 masks -------------------------------
__global__ void k_mask(float* __restrict__ out, const unsigned* __restrict__ st){
  unsigned Ta = st[28], ca = st[29];
  unsigned Tb = st[36], cb = st[37];
  unsigned tid = blockIdx.x*blockDim.x + threadIdx.x;
  unsigned stride = gridDim.x*blockDim.x;
  for (unsigned i = tid; i < HW; i += stride){
    unsigned oka = okey(out[i]);
    out[i] = (oka > Ta || (oka == Ta && i <= ca)) ? 1.0f : 0.0f;
    unsigned okb = okey(out[HW + i]);
    out[HW + i] = (okb > Tb || (okb == Tb && i <= cb)) ? 1.0f : 0.0f;
  }
}

extern "C" void kernel_launch(void* const* d_in, const int* in_sizes, int n_in,
                              void* d_out, int out_size, void* d_ws, size_t ws_size,
                              hipStream_t stream) {
  const float* cam = (const float*)d_in[0];
  const int*   roi = (const int*)d_in[1];
  float* out = (float*)d_out;

  uint8_t* w = (uint8_t*)d_ws;
  unsigned* h1a = (unsigned*)w;            // 4096 u32
  unsigned* h1b = h1a + 4096;
  unsigned* h2a = h1b + 4096;
  unsigned* h2b = h2a + 4096;              // ends at byte 65536
  unsigned* cnt = h2b + 4096;              // 16 u32 @ 65536
  unsigned* st  = cnt + 16;                // 240 u32 @ 65600
  unsigned long long* colA = (unsigned long long*)(w + 73728);  // CAP entries
  unsigned long long* colB = colA + CAP;

  // JAX: key(42) -> split -> k_fg, k_bg (partitionable/foldlike split)
  uint32_t kf0,kf1,kb0,kb1;
  threefry2x32(0u, 42u, 0u, 0u, kf0, kf1);
  threefry2x32(0u, 42u, 0u, 1u, kb0, kb1);

  // ---- round 0: candidate-set selection (cam order statistics) ----
  hipMemsetAsync(d_ws, 0, 66560, stream);                 // hists + cnt + state
  k_hist1_cand<<<512, 256, 0, stream>>>(cam, roi, h1a, h1b, st);
  k_fin1<<<1, 256, 0, stream>>>(h1a, h1b, st, 0);
  k_hist2_cand<<<512, 256, 0, stream>>>(cam, roi, st, h2a, h2b);
  k_fin2<<<1, 256, 0, stream>>>(h2a, h2b, st, 0);
  k_col_cand<<<512, 256, 0, stream>>>(cam, roi, st, colA, colB, cnt);
  k_fin3<<<1, 256, 0, stream>>>(colA, colB, cnt, st, 0);

  // ---- round 1: gumbel scores + top-5000 selection ----
  hipMemsetAsync(d_ws, 0, 65600, stream);                 // hists + cnt only (keep state)
  k_score<<<1024, 256, 0, stream>>>(cam, roi, st, out, h1a, h1b, kf0, kf1, kb0, kb1);
  k_fin1<<<1, 256, 0, stream>>>(h1a, h1b, st, 1);
  k_hist2_s<<<512, 256, 0, stream>>>(out, st, h2a, h2b);
  k_fin2<<<1, 256, 0, stream>>>(h2a, h2b, st, 1);
  k_col_s<<<512, 256, 0, stream>>>(out, st, colA, colB, cnt);
  k_fin3<<<1, 256, 0, stream>>>(colA, colB, cnt, st, 1);
  k_mask<<<512, 256, 0, stream>>>(out, st);
}